// Round 7
// baseline (838.001 us; speedup 1.0000x reference)
//
#include <hip/hip_runtime.h>
#include <math.h>

// ---------------------------------------------------------------------------
// HierarchicalVQEncoder forward.
//
// Eval mode: assign = hard one-hot (soft terms cancel), so out[b,t] depends
// ONLY on (idx1[b], idx2[b,t]) -> 8*32=256-row table + gather.
//
// idx2 = argmax_k [ r . H_all[i1][:,k] + f_all[i1][k] ],
//   r = relu(ln(x@Wl1^T+bl1))   (argmax invariant to positive scaling;
//   H,f fold Wl2,Wtb,btb,cb2; computed for ALL 8 i1 to break dependency)
//
// 3-kernel DAG:
//   A: x partial stats | tiled transposes (Wl1,Wg1,Wg2,Wp,Wf,Wfb) | fold H_all
//   B: global encoder -> idx1 (16 blocks) | output table (256 blocks)
//   C: main GEMM + LN + scores + argmax + table gather
//      v8: W OFF THE LDS PIPE. v0/v3/v7 all converged at ~272us = per-CU
//      ds_read_b128 throughput bound (~12cyc/instr, broadcast not deduped):
//      (r+c) reads per kg per wave. Now W is read straight from L1/L2 via
//      global float4 (1MB total, every block same addresses, kt-slice fits
//      L1) -> VMEM pipe (~32KB/kg/CU << L2 BW); LDS carries only x
//      (8 instr/kg/wave = 768 cyc/CU/kg < FMA 1024) -> FMA is critical pipe.
//      8x8 thread tile, TM=64, x dbuf 2x16KB (KB=64), 1 barrier/tile.
//
// Precision: big GEMM fp32, all folding math fp64.
// ---------------------------------------------------------------------------

#define TM 64
#define KB 64

typedef __attribute__((address_space(3))) void lds_void_t;
typedef const __attribute__((address_space(1))) void glb_void_t;

__device__ __forceinline__ void async_copy16(const float* g, float* l){
  __builtin_amdgcn_global_load_lds((glb_void_t*)g, (lds_void_t*)l, 16, 0, 0);
}

__device__ __forceinline__ double blk_sum_256(double v, double* red){
  const int tid = threadIdx.x;
  red[tid] = v; __syncthreads();
  #pragma unroll
  for(int s=128; s>0; s>>=1){ if(tid < s) red[tid] += red[tid+s]; __syncthreads(); }
  const double r = red[0]; __syncthreads();
  return r;
}

// ---- tiled 64x64 transpose helper (coalesced in AND out) ----------------
__device__ __forceinline__ void tile_transpose(
    const float* __restrict__ src, float* __restrict__ dst,
    int M, int N, int tile_id, float (*tile)[65]){
  const int tpr = N >> 6;
  const int r0 = (tile_id / tpr) << 6;
  const int c0 = (tile_id % tpr) << 6;
  const int t = threadIdx.x;
  {
    const int i = t >> 4, j4 = (t & 15) << 2;
    #pragma unroll
    for(int q=0;q<4;q++){
      const int row = i + (q<<4);
      const float4 v = *(const float4*)&src[(size_t)(r0+row)*N + c0 + j4];
      tile[row][j4+0]=v.x; tile[row][j4+1]=v.y; tile[row][j4+2]=v.z; tile[row][j4+3]=v.w;
    }
  }
  __syncthreads();
  {
    const int j = t >> 4, i4 = (t & 15) << 2;
    #pragma unroll
    for(int q=0;q<4;q++){
      const int col = j + (q<<4);
      float4 o;
      o.x = tile[i4+0][col]; o.y = tile[i4+1][col];
      o.z = tile[i4+2][col]; o.w = tile[i4+3][col];
      *(float4*)&dst[(size_t)(c0+col)*M + r0 + i4] = o;
    }
  }
}

// ========================= Kernel A (488 blocks) =========================
union SmemA {
  float tile[64][65];
  struct { double Wcs[64][33]; double bcs[64]; double cbd[32][64]; double nrm[32]; } fold;
};

__global__ __launch_bounds__(256) void hvq_A(
    const float* __restrict__ x,
    const float* __restrict__ Wl1, const float* __restrict__ Wg1,
    const float* __restrict__ Wf,  const float* __restrict__ Wfb,
    const float* __restrict__ Wg2, const float* __restrict__ Wp,
    const float* __restrict__ Wtb, const float* __restrict__ Wl2,
    const float* __restrict__ bl2, const float* __restrict__ btb,
    const float* __restrict__ cb2,
    double* __restrict__ psum, double* __restrict__ psumsq,
    float* __restrict__ Wl1T, float* __restrict__ Wg1T,
    float* __restrict__ WfT,  float* __restrict__ WfbT,
    float* __restrict__ Wg2T, float* __restrict__ WpT,
    float* __restrict__ H_all, float* __restrict__ f_all){
  __shared__ SmemA sm;
  const int blk = blockIdx.x;
  const int tid = threadIdx.x;

  if(blk < 256){
    const int tc = blk & 15, b = blk >> 4;
    const int d4 = tid * 4;
    const float* xp = x + ((size_t)(b*2048 + tc*128))*1024 + d4;
    double s0=0,s1=0,s2=0,s3=0, q0=0,q1=0,q2=0,q3=0;
    for(int t=0;t<128;t++){
      const float4 v = *(const float4*)&xp[(size_t)t*1024];
      s0 += v.x; q0 += (double)v.x*v.x;
      s1 += v.y; q1 += (double)v.y*v.y;
      s2 += v.z; q2 += (double)v.z*v.z;
      s3 += v.w; q3 += (double)v.w*v.w;
    }
    const size_t o = ((size_t)(b*16+tc))*1024 + d4;
    psum[o+0]=s0; psum[o+1]=s1; psum[o+2]=s2; psum[o+3]=s3;
    psumsq[o+0]=q0; psumsq[o+1]=q1; psumsq[o+2]=q2; psumsq[o+3]=q3;
  } else if(blk < 320){
    tile_transpose(Wl1, Wl1T, 256, 1024, blk-256, sm.tile);
  } else if(blk < 384){
    tile_transpose(Wg1, Wg1T, 256, 1024, blk-320, sm.tile);
  } else if(blk < 408){
    tile_transpose(Wf,  WfT,  256, 384,  blk-384, sm.tile);
  } else if(blk < 412){
    tile_transpose(Wfb, WfbT, 256, 64,   blk-408, sm.tile);
  } else if(blk < 420){
    tile_transpose(Wg2, Wg2T, 128, 256,  blk-412, sm.tile);
  } else if(blk < 424){
    tile_transpose(Wp,  WpT,  128, 128,  blk-420, sm.tile);
  } else {
    const int fb = blk - 424;
    const int ng = fb & 7;
    const int i1 = fb >> 3;
    const int tn = tid & 31;
    const int kq = tid >> 5;
    const int n  = ng*32 + tn;

    if(tid < 32){
      const float* cr = cb2 + ((size_t)i1*32 + tid)*64;
      double n2 = 0;
      for(int c=0;c<64;c++){ const double v=(double)cr[c]; n2 += v*v; }
      sm.fold.nrm[tid] = fmax(sqrt(n2), 1e-12);
    }
    __syncthreads();
    for(int i=tid;i<2048;i+=256){
      const int k = i >> 6, c = i & 63;
      sm.fold.cbd[k][c] = (double)cb2[((size_t)i1*32+k)*64 + c] / sm.fold.nrm[k];
    }
    {
      double acc[8] = {0,0,0,0,0,0,0,0};
      const float* wt = Wtb + (size_t)(kq*8)*256;
      for(int j=0;j<256;j++){
        const double wl = (double)Wl2[(size_t)j*256 + n];
        #pragma unroll
        for(int cc=0;cc<8;cc++) acc[cc] += (double)wt[cc*256 + j] * wl;
      }
      #pragma unroll
      for(int cc=0;cc<8;cc++) sm.fold.Wcs[kq*8+cc][tn] = acc[cc];
    }
    if(tid < 64){
      const float* wt = Wtb + (size_t)tid*256;
      double a = 0;
      for(int j=0;j<256;j++) a += (double)wt[j]*(double)bl2[j];
      sm.fold.bcs[tid] = a + (double)btb[tid];
    }
    __syncthreads();

    double su = 0;
    for(int c=0;c<64;c++) su += sm.fold.Wcs[c][tn];
    su /= 64.0;
    for(int t=0;t<4;t++){
      const int k = kq*4 + t;
      double acc=0, sk=0;
      for(int c=0;c<64;c++){ const double cc = sm.fold.cbd[k][c]; acc += sm.fold.Wcs[c][tn]*cc; sk += cc; }
      H_all[((size_t)i1*256 + n)*32 + k] = (float)(acc - su*sk);
    }
    if(ng == 0 && tid < 32){
      const int k = tid;
      double acc=0, sk=0, sbc=0;
      for(int c=0;c<64;c++){ const double cc = sm.fold.cbd[k][c]; acc += sm.fold.bcs[c]*cc; sk += cc; sbc += sm.fold.bcs[c]; }
      f_all[i1*32 + k] = (float)(acc - (sbc/64.0)*sk);
    }
  }
}

// ========================= Kernel B (272 blocks) =========================
union SmemB {
  struct { float gin[1024]; float sa[256]; float sb[128]; float sh[128];
           double red[256]; double lg[8]; int i1s; } p2;
  struct { float e[64]; float fused[384]; double red[256]; } p4;
};

__global__ __launch_bounds__(256) void hvq_B(
    const double* __restrict__ psum, const double* __restrict__ psumsq,
    const float* __restrict__ Wg1T, const float* __restrict__ bg1,
    const float* __restrict__ Wg2T, const float* __restrict__ bg2,
    const float* __restrict__ WpT,  const float* __restrict__ bp,
    const float* __restrict__ cb1,  const float* __restrict__ cb2,
    const float* __restrict__ WfbT, const float* __restrict__ bfb,
    const float* __restrict__ WfT,  const float* __restrict__ bf,
    int* __restrict__ idx1_g, float* __restrict__ table){
  __shared__ SmemB sm;
  const int tid = threadIdx.x;

  if(blockIdx.x < 16){
    const int b = blockIdx.x;
    for(int i=tid;i<1024;i+=256){
      double s=0, ss=0;
      for(int tc=0;tc<16;tc++){
        const size_t o = ((size_t)(b*16+tc))*1024 + i;
        s += psum[o]; ss += psumsq[o];
      }
      const double mean = s / 2048.0;
      double var = (ss - s*mean) / 2047.0;
      if(var < 0) var = 0;
      sm.p2.gin[i] = (float)(mean + sqrt(var));
    }
    __syncthreads();

    double z = 0;
    {
      #pragma unroll 8
      for(int k=0;k<1024;k++) z += (double)sm.p2.gin[k] * (double)Wg1T[(size_t)k*256 + tid];
      z += (double)bg1[tid];
    }
    const double mz = blk_sum_256(z, sm.p2.red) / 256.0;
    const double dz = z - mz;
    const double vz = blk_sum_256(dz*dz, sm.p2.red) / 256.0;
    double a = dz / sqrt(vz + 1e-5);
    if(a < 0) a = 0;
    sm.p2.sa[tid] = (float)a;
    __syncthreads();

    if(tid < 128){
      double g = 0;
      #pragma unroll 8
      for(int i=0;i<256;i++) g += (double)sm.p2.sa[i]*(double)Wg2T[(size_t)i*128 + tid];
      sm.p2.sb[tid] = (float)(g + (double)bg2[tid]);
    }
    __syncthreads();

    double h = 0;
    if(tid < 128){
      #pragma unroll 8
      for(int i=0;i<128;i++) h += (double)sm.p2.sb[i]*(double)WpT[(size_t)i*128 + tid];
      h += (double)bp[tid];
    }
    const double mh = blk_sum_256(tid<128 ? h : 0.0, sm.p2.red) / 128.0;
    const double dh = (tid<128) ? (h - mh) : 0.0;
    const double vh = blk_sum_256(dh*dh, sm.p2.red) / 128.0;
    const double h1 = dh / sqrt(vh + 1e-5);
    if(tid < 128) sm.p2.sh[tid] = (float)h1;
    const double nh2 = blk_sum_256(tid<128 ? h1*h1 : 0.0, sm.p2.red);
    const double normh = sqrt(nh2);
    __syncthreads();

    if(tid < 8){
      const float* cr = cb1 + tid*128;
      double dsum=0, n2=0;
      for(int i=0;i<128;i++){ const double c=(double)cr[i]; dsum += (double)sm.p2.sh[i]*c; n2 += c*c; }
      sm.p2.lg[tid] = dsum / (fmax(normh,1e-12) * fmax(sqrt(n2),1e-12));
    }
    __syncthreads();
    if(tid == 0){
      int bi=0; double bv=sm.p2.lg[0];
      for(int j=1;j<8;j++) if(sm.p2.lg[j] > bv){ bv=sm.p2.lg[j]; bi=j; }
      idx1_g[b] = bi;
    }
  } else {
    const int row = blockIdx.x - 16;
    const int i1 = row >> 5, k2 = row & 31;
    const int j = tid;
    if(j < 64) sm.p4.e[j] = cb2[((size_t)i1*32 + k2)*64 + j];
    if(j >= 128 && j < 256) sm.p4.fused[256 + (j-128)] = cb1[i1*128 + (j-128)];
    __syncthreads();

    double t = 0;
    {
      #pragma unroll 8
      for(int c=0;c<64;c++) t += (double)sm.p4.e[c]*(double)WfbT[(size_t)c*256 + j];
      t += (double)bfb[j];
    }
    double m = blk_sum_256(t, sm.p4.red) / 256.0;
    double d = t - m;
    double v = blk_sum_256(d*d, sm.p4.red) / 256.0;
    sm.p4.fused[j] = (float)(d / sqrt(v + 1e-5));
    __syncthreads();

    double o = 0;
    {
      #pragma unroll 8
      for(int i=0;i<384;i++) o += (double)sm.p4.fused[i]*(double)WfT[(size_t)i*256 + j];
      o += (double)bf[j];
    }
    m = blk_sum_256(o, sm.p4.red) / 256.0;
    d = o - m;
    v = blk_sum_256(d*d, sm.p4.red) / 256.0;
    double r = d / sqrt(v + 1e-5);
    if(r < 0) r = 0;
    table[(size_t)row*256 + j] = (float)r;
  }
}

// ========================= Kernel C: main (TM=64, W from L2) =============
// v8: 256 threads = 32 tx x 8 ty; thread tile 8 rows (ty*8+j) x 8 cols
// (tx*4+c, 128+tx*4+c). x staged in LDS (dbuf 2 x [64][64] fp32 = 32KB,
// one barrier per kt); W read DIRECTLY from global Wl1T[k][256] as float4
// (same addresses for every block -> L1/L2-served; VMEM pipe, not LDS).
// Grid 32x16 = 512 blocks = 2 blocks/CU = 8 waves/CU.
// Epilogue: v0's proven two-half rT (stride 36) + argmax + table gather.
#define XTILE (TM*KB)   // 4096 floats = 16KB per buffer

__global__ __launch_bounds__(256) void hvq_main(
    const float* __restrict__ x, const float* __restrict__ Wl1T,
    const float* __restrict__ bl1, const float* __restrict__ H_all,
    const float* __restrict__ f_all, const int* __restrict__ idx1,
    const float* __restrict__ table, float* __restrict__ out){
  __shared__ float smem[9248];             // 36992 B: x dbuf 8192f | rT 9216f alias
  float* rT  = smem;                       // [n][36] epilogue, 9216 floats
  int* kstar = (int*)&smem[9216];          // 64 ints? 32 used; epilogue-only

  const int tid = threadIdx.x;
  const int tx = tid & 31, ty = tid >> 5;  // 8 rows: ty*8+j; cols tx*4 quads
  const int b  = blockIdx.y;
  const int t0 = blockIdx.x * TM;
  const int i1 = idx1[b];

  float acc[8][8];
  #pragma unroll
  for(int j=0;j<8;j++)
    #pragma unroll
    for(int c=0;c<8;c++) acc[j][c] = 0.f;

  float bn[8];
  #pragma unroll
  for(int c=0;c<4;c++){ bn[c] = bl1[tx*4+c]; bn[c+4] = bl1[128 + tx*4 + c]; }

  // x staging: 4 insts/thread per kt; inst i covers floats [i*1024,+1024) of
  // the [64 rows][64 k] tile: row = i*16 + (tid>>4), k = (tid&15)*4.
  // LDS dst = i*1024 + tid*4  (wave-uniform base + lane*16B).
  const float* xsrc = x + ((size_t)(b*2048 + t0 + (tid>>4)))*1024 + (tid&15)*4;
  auto stage = [&](int kt, float* buf) __attribute__((always_inline)) {
    #pragma unroll
    for(int i=0;i<4;i++)
      async_copy16(xsrc + (size_t)i*16*1024 + kt*KB, buf + i*1024 + tid*4);
  };

  stage(0, smem);

  for(int kt=0; kt<1024/KB; kt++){
    __syncthreads();   // tile kt landed (vmcnt drain) + compute(kt-1) done
    const float* xs = smem + (kt&1)*XTILE;     // [row][64]
    if(kt+1 < 1024/KB) stage(kt+1, smem + ((kt+1)&1)*XTILE);

    const float* Wt = Wl1T + (size_t)kt*KB*256;   // [kk][256], L1/L2-hot
    #pragma unroll 4
    for(int kg=0; kg<KB/4; kg++){
      float4 xv[8];
      #pragma unroll
      for(int j=0;j<8;j++) xv[j] = *(const float4*)&xs[(ty*8+j)*KB + kg*4];
      #pragma unroll
      for(int t=0;t<4;t++){
        const float* wk = Wt + (size_t)(kg*4 + t)*256;
        const float4 w0 = *(const float4*)&wk[tx*4];          // global: L1/L2
        const float4 w1 = *(const float4*)&wk[128 + tx*4];
        #pragma unroll
        for(int j=0;j<8;j++){
          const float xvj = (&xv[j].x)[t];
          acc[j][0] = fmaf(xvj, w0.x, acc[j][0]);
          acc[j][1] = fmaf(xvj, w0.y, acc[j][1]);
          acc[j][2] = fmaf(xvj, w0.z, acc[j][2]);
          acc[j][3] = fmaf(xvj, w0.w, acc[j][3]);
          acc[j][4] = fmaf(xvj, w1.x, acc[j][4]);
          acc[j][5] = fmaf(xvj, w1.y, acc[j][5]);
          acc[j][6] = fmaf(xvj, w1.z, acc[j][6]);
          acc[j][7] = fmaf(xvj, w1.w, acc[j][7]);
        }
      }
    }
  }

  // bias + LN(256) per row (reduce across 32 tx lanes) + ReLU, in registers
  #pragma unroll
  for(int j=0;j<8;j++){
    float s = 0.f;
    #pragma unroll
    for(int c=0;c<8;c++){ acc[j][c] += bn[c]; s += acc[j][c]; }
    #pragma unroll
    for(int off=16;off>=1;off>>=1) s += __shfl_xor(s, off);
    const float mean = s * (1.f/256.f);
    float d2 = 0.f;
    #pragma unroll
    for(int c=0;c<8;c++){ const float dv = acc[j][c]-mean; d2 += dv*dv; }
    #pragma unroll
    for(int off=16;off>=1;off>>=1) d2 += __shfl_xor(d2, off);
    const float inv = 1.f / sqrtf(d2*(1.f/256.f) + 1e-5f);
    #pragma unroll
    for(int c=0;c<8;c++) acc[j][c] = fmaxf((acc[j][c]-mean)*inv, 0.f);
  }

  // scores in two 32-row halves (rT = 32 rows x 256 n, stride 36)
  const int k = tid & 31, mg = tid >> 5;
  const float* Hb = H_all + (size_t)i1*256*32 + k;
  const float fk = f_all[i1*32 + k];
  const int half_owner = ty >> 2;        // which half this thread's rows are in
  const int mm_base = (ty & 3)*8;

  for(int h=0; h<2; h++){
    __syncthreads();                     // prior phase reads done / K-loop done
    if(half_owner == h){
      #pragma unroll
      for(int j=0;j<8;j++){
        #pragma unroll
        for(int c=0;c<8;c++){
          const int n = (c < 4) ? (tx*4 + c) : (128 + tx*4 + (c-4));
          rT[n*36 + mm_base + j] = acc[j][c];
        }
      }
    }
    __syncthreads();

    float s0=fk, s1=fk, s2=fk, s3=fk;
    #pragma unroll 4
    for(int n=0;n<256;n++){
      const float4 rm = *(const float4*)&rT[n*36 + mg*4];
      const float hv = Hb[(size_t)n*32];
      s0 = fmaf(rm.x, hv, s0);
      s1 = fmaf(rm.y, hv, s1);
      s2 = fmaf(rm.z, hv, s2);
      s3 = fmaf(rm.w, hv, s3);
    }
    float scv[4] = {s0, s1, s2, s3};
    #pragma unroll
    for(int j=0;j<4;j++){
      float best = scv[j]; int bi = k;
      #pragma unroll
      for(int off=16;off>=1;off>>=1){
        const float ov = __shfl_xor(best, off);
        const int   oi = __shfl_xor(bi, off);
        if(ov > best || (ov == best && oi < bi)){ best = ov; bi = oi; }
      }
      if(k == 0) kstar[h*32 + mg*4 + j] = bi;
    }
  }
  __syncthreads();

  float* ob = out + ((size_t)(b*2048 + t0))*256;
  for(int m=0;m<TM;m++){
    const float v = table[((size_t)(i1*32 + kstar[m]))*256 + tid];
    ob[(size_t)m*256 + tid] = v;
  }
}

// ---------------------------------------------------------------------------
extern "C" void kernel_launch(void* const* d_in, const int* in_sizes, int n_in,
                              void* d_out, int out_size, void* d_ws, size_t ws_size,
                              hipStream_t stream){
  const float* x   = (const float*)d_in[0];
  const float* Wg1 = (const float*)d_in[1];
  const float* bg1 = (const float*)d_in[2];
  const float* Wg2 = (const float*)d_in[3];
  const float* bg2 = (const float*)d_in[4];
  const float* Wl1 = (const float*)d_in[5];
  const float* bl1 = (const float*)d_in[6];
  const float* Wl2 = (const float*)d_in[7];
  const float* bl2 = (const float*)d_in[8];
  const float* Wp  = (const float*)d_in[9];
  const float* bp  = (const float*)d_in[10];
  const float* cb1 = (const float*)d_in[11];
  const float* Wtb = (const float*)d_in[12];
  const float* btb = (const float*)d_in[13];
  const float* Wfb = (const float*)d_in[14];
  const float* bfb = (const float*)d_in[15];
  const float* cb2 = (const float*)d_in[16];
  const float* Wf  = (const float*)d_in[17];
  const float* bf  = (const float*)d_in[18];
  float* out = (float*)d_out;

  char* w = (char*)d_ws;
  double* psum   = (double*)w; w += (size_t)16*16*1024*8;   // 2 MB
  double* psumsq = (double*)w; w += (size_t)16*16*1024*8;   // 2 MB
  float*  Wl1T   = (float*)w;  w += (size_t)1024*256*4;     // 1 MB
  float*  Wg1T   = (float*)w;  w += (size_t)1024*256*4;     // 1 MB
  float*  WfT    = (float*)w;  w += (size_t)384*256*4;
  float*  WfbT   = (float*)w;  w += (size_t)64*256*4;
  float*  Wg2T   = (float*)w;  w += (size_t)256*128*4;
  float*  WpT    = (float*)w;  w += (size_t)128*128*4;
  float*  H_all  = (float*)w;  w += (size_t)8*256*32*4;     // 256 KB
  float*  f_all  = (float*)w;  w += (size_t)8*32*4;
  float*  table  = (float*)w;  w += (size_t)256*256*4;      // 256 KB
  int*    idx1   = (int*)w;    w += 64;

  hvq_A<<<488, 256, 0, stream>>>(x, Wl1, Wg1, Wf, Wfb, Wg2, Wp, Wtb, Wl2, bl2, btb, cb2,
                                 psum, psumsq, Wl1T, Wg1T, WfT, WfbT, Wg2T, WpT,
                                 H_all, f_all);
  hvq_B<<<272, 256, 0, stream>>>(psum, psumsq, Wg1T, bg1, Wg2T, bg2, WpT, bp, cb1, cb2,
                                 WfbT, bfb, WfT, bf, idx1, table);
  hvq_main<<<dim3(32,16), 256, 0, stream>>>(x, Wl1T, bl1, H_all, f_all, idx1, table, out);
}

// Round 8
// 459.064 us; speedup vs baseline: 1.8255x; 1.8255x over previous
//
#include <hip/hip_runtime.h>
#include <math.h>

// ---------------------------------------------------------------------------
// HierarchicalVQEncoder forward.
//
// Eval mode: assign = hard one-hot (soft terms cancel), so out[b,t] depends
// ONLY on (idx1[b], idx2[b,t]) -> 8*32=256-row table + gather.
//
// idx2 = argmax_k [ r . H_all[i1][:,k] + f_all[i1][k] ],
//   r = relu(ln(x@Wl1^T+bl1))
//
// v9: MAIN GEMM ON THE MATRIX PIPE. fp32 VALU GEMM plateaued at ~272us
// across 4 structures (VALUBusy~55%, ~150us of VALU issue vs 109us FMA
// floor + unhidable stall). Split x,W into bf16 hi + bf16 residual (RNE),
// compute all 4 cross products with mfma_f32_16x16x32_bf16 into fp32 acc
// (error ~2^-18 rel, ~fp32-class). 4x17.2GF at 2075TF ubench = 33us floor.
//   A: + split Wl1 (native [col][k] = B-frag layout!) -> Whg/Wlg bf16.
//   C: per block 64 rows x 256 cols; 4 waves x 16 rows x 256 cols
//      (LN stays wave-local). x staged f32 via global_load_lds with
//      source-preswizzled chunk XOR; W slices staged bf16 (32KB/kt).
//      A-frags: ds_read f32 + on-the-fly split (VALU pipe, hidden under
//      MFMA). Epilogue: rT[256][68] (64 rows) + v0's scores/argmax/gather.
// ---------------------------------------------------------------------------

typedef __attribute__((address_space(3))) void lds_void_t;
typedef const __attribute__((address_space(1))) void glb_void_t;

typedef __attribute__((ext_vector_type(8))) short bf16x8;
typedef __attribute__((ext_vector_type(4))) float f32x4;

__device__ __forceinline__ void async_copy16(const float* g, float* l){
  __builtin_amdgcn_global_load_lds((glb_void_t*)g, (lds_void_t*)l, 16, 0, 0);
}

__device__ __forceinline__ unsigned bf16_rne(float v){
  const unsigned u = __float_as_uint(v);
  return (u + 0x7FFFu + ((u >> 16) & 1u)) >> 16;
}

union PackB { unsigned u[4]; bf16x8 v; };

__device__ __forceinline__ void split_f32x8(float4 a, float4 b, bf16x8& h, bf16x8& l){
  float f[8] = {a.x,a.y,a.z,a.w,b.x,b.y,b.z,b.w};
  unsigned hu[8], lu[8];
  #pragma unroll
  for(int i=0;i<8;i++){
    hu[i] = bf16_rne(f[i]);
    const float r = f[i] - __uint_as_float(hu[i] << 16);
    lu[i] = bf16_rne(r);
  }
  PackB H, L;
  #pragma unroll
  for(int i=0;i<4;i++){
    H.u[i] = hu[2*i] | (hu[2*i+1] << 16);
    L.u[i] = lu[2*i] | (lu[2*i+1] << 16);
  }
  h = H.v; l = L.v;
}

__device__ __forceinline__ double blk_sum_256(double v, double* red){
  const int tid = threadIdx.x;
  red[tid] = v; __syncthreads();
  #pragma unroll
  for(int s=128; s>0; s>>=1){ if(tid < s) red[tid] += red[tid+s]; __syncthreads(); }
  const double r = red[0]; __syncthreads();
  return r;
}

// ---- tiled 64x64 transpose helper (coalesced in AND out) ----------------
__device__ __forceinline__ void tile_transpose(
    const float* __restrict__ src, float* __restrict__ dst,
    int M, int N, int tile_id, float (*tile)[65]){
  const int tpr = N >> 6;
  const int r0 = (tile_id / tpr) << 6;
  const int c0 = (tile_id % tpr) << 6;
  const int t = threadIdx.x;
  {
    const int i = t >> 4, j4 = (t & 15) << 2;
    #pragma unroll
    for(int q=0;q<4;q++){
      const int row = i + (q<<4);
      const float4 v = *(const float4*)&src[(size_t)(r0+row)*N + c0 + j4];
      tile[row][j4+0]=v.x; tile[row][j4+1]=v.y; tile[row][j4+2]=v.z; tile[row][j4+3]=v.w;
    }
  }
  __syncthreads();
  {
    const int j = t >> 4, i4 = (t & 15) << 2;
    #pragma unroll
    for(int q=0;q<4;q++){
      const int col = j + (q<<4);
      float4 o;
      o.x = tile[i4+0][col]; o.y = tile[i4+1][col];
      o.z = tile[i4+2][col]; o.w = tile[i4+3][col];
      *(float4*)&dst[(size_t)(c0+col)*M + r0 + i4] = o;
    }
  }
}

// ========================= Kernel A (496 blocks) =========================
// [0,256) p1 stats | [256,424) transposes | [424,488) fold | [488,496) Wsplit
union SmemA {
  float tile[64][65];
  struct { double Wcs[64][33]; double bcs[64]; double cbd[32][64]; double nrm[32]; } fold;
};

__global__ __launch_bounds__(256) void hvq_A(
    const float* __restrict__ x,
    const float* __restrict__ Wl1, const float* __restrict__ Wg1,
    const float* __restrict__ Wf,  const float* __restrict__ Wfb,
    const float* __restrict__ Wg2, const float* __restrict__ Wp,
    const float* __restrict__ Wtb, const float* __restrict__ Wl2,
    const float* __restrict__ bl2, const float* __restrict__ btb,
    const float* __restrict__ cb2,
    double* __restrict__ psum, double* __restrict__ psumsq,
    float* __restrict__ Wl1T, float* __restrict__ Wg1T,
    float* __restrict__ WfT,  float* __restrict__ WfbT,
    float* __restrict__ Wg2T, float* __restrict__ WpT,
    float* __restrict__ H_all, float* __restrict__ f_all,
    unsigned short* __restrict__ Whg, unsigned short* __restrict__ Wlg){
  __shared__ SmemA sm;
  const int blk = blockIdx.x;
  const int tid = threadIdx.x;

  if(blk < 256){
    const int tc = blk & 15, b = blk >> 4;
    const int d4 = tid * 4;
    const float* xp = x + ((size_t)(b*2048 + tc*128))*1024 + d4;
    double s0=0,s1=0,s2=0,s3=0, q0=0,q1=0,q2=0,q3=0;
    for(int t=0;t<128;t++){
      const float4 v = *(const float4*)&xp[(size_t)t*1024];
      s0 += v.x; q0 += (double)v.x*v.x;
      s1 += v.y; q1 += (double)v.y*v.y;
      s2 += v.z; q2 += (double)v.z*v.z;
      s3 += v.w; q3 += (double)v.w*v.w;
    }
    const size_t o = ((size_t)(b*16+tc))*1024 + d4;
    psum[o+0]=s0; psum[o+1]=s1; psum[o+2]=s2; psum[o+3]=s3;
    psumsq[o+0]=q0; psumsq[o+1]=q1; psumsq[o+2]=q2; psumsq[o+3]=q3;
  } else if(blk < 320){
    tile_transpose(Wl1, Wl1T, 256, 1024, blk-256, sm.tile);
  } else if(blk < 384){
    tile_transpose(Wg1, Wg1T, 256, 1024, blk-320, sm.tile);
  } else if(blk < 408){
    tile_transpose(Wf,  WfT,  256, 384,  blk-384, sm.tile);
  } else if(blk < 412){
    tile_transpose(Wfb, WfbT, 256, 64,   blk-408, sm.tile);
  } else if(blk < 420){
    tile_transpose(Wg2, Wg2T, 128, 256,  blk-412, sm.tile);
  } else if(blk < 424){
    tile_transpose(Wp,  WpT,  128, 128,  blk-420, sm.tile);
  } else if(blk < 488){
    const int fb = blk - 424;
    const int ng = fb & 7;
    const int i1 = fb >> 3;
    const int tn = tid & 31;
    const int kq = tid >> 5;
    const int n  = ng*32 + tn;

    if(tid < 32){
      const float* cr = cb2 + ((size_t)i1*32 + tid)*64;
      double n2 = 0;
      for(int c=0;c<64;c++){ const double v=(double)cr[c]; n2 += v*v; }
      sm.fold.nrm[tid] = fmax(sqrt(n2), 1e-12);
    }
    __syncthreads();
    for(int i=tid;i<2048;i+=256){
      const int k = i >> 6, c = i & 63;
      sm.fold.cbd[k][c] = (double)cb2[((size_t)i1*32+k)*64 + c] / sm.fold.nrm[k];
    }
    {
      double acc[8] = {0,0,0,0,0,0,0,0};
      const float* wt = Wtb + (size_t)(kq*8)*256;
      for(int j=0;j<256;j++){
        const double wl = (double)Wl2[(size_t)j*256 + n];
        #pragma unroll
        for(int cc=0;cc<8;cc++) acc[cc] += (double)wt[cc*256 + j] * wl;
      }
      #pragma unroll
      for(int cc=0;cc<8;cc++) sm.fold.Wcs[kq*8+cc][tn] = acc[cc];
    }
    if(tid < 64){
      const float* wt = Wtb + (size_t)tid*256;
      double a = 0;
      for(int j=0;j<256;j++) a += (double)wt[j]*(double)bl2[j];
      sm.fold.bcs[tid] = a + (double)btb[tid];
    }
    __syncthreads();

    double su = 0;
    for(int c=0;c<64;c++) su += sm.fold.Wcs[c][tn];
    su /= 64.0;
    for(int t=0;t<4;t++){
      const int k = kq*4 + t;
      double acc=0, sk=0;
      for(int c=0;c<64;c++){ const double cc = sm.fold.cbd[k][c]; acc += sm.fold.Wcs[c][tn]*cc; sk += cc; }
      H_all[((size_t)i1*256 + n)*32 + k] = (float)(acc - su*sk);
    }
    if(ng == 0 && tid < 32){
      const int k = tid;
      double acc=0, sk=0, sbc=0;
      for(int c=0;c<64;c++){ const double cc = sm.fold.cbd[k][c]; acc += sm.fold.bcs[c]*cc; sk += cc; sbc += sm.fold.bcs[c]; }
      f_all[i1*32 + k] = (float)(acc - (sbc/64.0)*sk);
    }
  } else {
    // ---- Wl1 bf16 hi/lo split: Wl1 is (256,1024) row-major = [col][k] ----
    const int base = (blk - 488) * 32768;
    for(int i=tid; i<32768; i+=256){
      const float v = Wl1[base + i];
      const unsigned h = bf16_rne(v);
      const float r = v - __uint_as_float(h << 16);
      const unsigned lo = bf16_rne(r);
      Whg[base + i] = (unsigned short)h;
      Wlg[base + i] = (unsigned short)lo;
    }
  }
}

// ========================= Kernel B (272 blocks) =========================
union SmemB {
  struct { float gin[1024]; float sa[256]; float sb[128]; float sh[128];
           double red[256]; double lg[8]; int i1s; } p2;
  struct { float e[64]; float fused[384]; double red[256]; } p4;
};

__global__ __launch_bounds__(256) void hvq_B(
    const double* __restrict__ psum, const double* __restrict__ psumsq,
    const float* __restrict__ Wg1T, const float* __restrict__ bg1,
    const float* __restrict__ Wg2T, const float* __restrict__ bg2,
    const float* __restrict__ WpT,  const float* __restrict__ bp,
    const float* __restrict__ cb1,  const float* __restrict__ cb2,
    const float* __restrict__ WfbT, const float* __restrict__ bfb,
    const float* __restrict__ WfT,  const float* __restrict__ bf,
    int* __restrict__ idx1_g, float* __restrict__ table){
  __shared__ SmemB sm;
  const int tid = threadIdx.x;

  if(blockIdx.x < 16){
    const int b = blockIdx.x;
    for(int i=tid;i<1024;i+=256){
      double s=0, ss=0;
      for(int tc=0;tc<16;tc++){
        const size_t o = ((size_t)(b*16+tc))*1024 + i;
        s += psum[o]; ss += psumsq[o];
      }
      const double mean = s / 2048.0;
      double var = (ss - s*mean) / 2047.0;
      if(var < 0) var = 0;
      sm.p2.gin[i] = (float)(mean + sqrt(var));
    }
    __syncthreads();

    double z = 0;
    {
      #pragma unroll 8
      for(int k=0;k<1024;k++) z += (double)sm.p2.gin[k] * (double)Wg1T[(size_t)k*256 + tid];
      z += (double)bg1[tid];
    }
    const double mz = blk_sum_256(z, sm.p2.red) / 256.0;
    const double dz = z - mz;
    const double vz = blk_sum_256(dz*dz, sm.p2.red) / 256.0;
    double a = dz / sqrt(vz + 1e-5);
    if(a < 0) a = 0;
    sm.p2.sa[tid] = (float)a;
    __syncthreads();

    if(tid < 128){
      double g = 0;
      #pragma unroll 8
      for(int i=0;i<256;i++) g += (double)sm.p2.sa[i]*(double)Wg2T[(size_t)i*128 + tid];
      sm.p2.sb[tid] = (float)(g + (double)bg2[tid]);
    }
    __syncthreads();

    double h = 0;
    if(tid < 128){
      #pragma unroll 8
      for(int i=0;i<128;i++) h += (double)sm.p2.sb[i]*(double)WpT[(size_t)i*128 + tid];
      h += (double)bp[tid];
    }
    const double mh = blk_sum_256(tid<128 ? h : 0.0, sm.p2.red) / 128.0;
    const double dh = (tid<128) ? (h - mh) : 0.0;
    const double vh = blk_sum_256(dh*dh, sm.p2.red) / 128.0;
    const double h1 = dh / sqrt(vh + 1e-5);
    if(tid < 128) sm.p2.sh[tid] = (float)h1;
    const double nh2 = blk_sum_256(tid<128 ? h1*h1 : 0.0, sm.p2.red);
    const double normh = sqrt(nh2);
    __syncthreads();

    if(tid < 8){
      const float* cr = cb1 + tid*128;
      double dsum=0, n2=0;
      for(int i=0;i<128;i++){ const double c=(double)cr[i]; dsum += (double)sm.p2.sh[i]*c; n2 += c*c; }
      sm.p2.lg[tid] = dsum / (fmax(normh,1e-12) * fmax(sqrt(n2),1e-12));
    }
    __syncthreads();
    if(tid == 0){
      int bi=0; double bv=sm.p2.lg[0];
      for(int j=1;j<8;j++) if(sm.p2.lg[j] > bv){ bv=sm.p2.lg[j]; bi=j; }
      idx1_g[b] = bi;
    }
  } else {
    const int row = blockIdx.x - 16;
    const int i1 = row >> 5, k2 = row & 31;
    const int j = tid;
    if(j < 64) sm.p4.e[j] = cb2[((size_t)i1*32 + k2)*64 + j];
    if(j >= 128 && j < 256) sm.p4.fused[256 + (j-128)] = cb1[i1*128 + (j-128)];
    __syncthreads();

    double t = 0;
    {
      #pragma unroll 8
      for(int c=0;c<64;c++) t += (double)sm.p4.e[c]*(double)WfbT[(size_t)c*256 + j];
      t += (double)bfb[j];
    }
    double m = blk_sum_256(t, sm.p4.red) / 256.0;
    double d = t - m;
    double v = blk_sum_256(d*d, sm.p4.red) / 256.0;
    sm.p4.fused[j] = (float)(d / sqrt(v + 1e-5));
    __syncthreads();

    double o = 0;
    {
      #pragma unroll 8
      for(int i=0;i<384;i++) o += (double)sm.p4.fused[i]*(double)WfT[(size_t)i*256 + j];
      o += (double)bf[j];
    }
    m = blk_sum_256(o, sm.p4.red) / 256.0;
    d = o - m;
    v = blk_sum_256(d*d, sm.p4.red) / 256.0;
    double r = d / sqrt(v + 1e-5);
    if(r < 0) r = 0;
    table[(size_t)row*256 + j] = (float)r;
  }
}

// ========================= Kernel C: main (MFMA) =========================
// Block = 64 rows x 256 cols, 4 waves, wave w: rows w*16..+15 x all 256 cols
// (16 coltiles). Per kt (K=32): stage Wh/Wl bf16 slices [256][32] (32KB,
// global_load_lds) + x f32 [64][32] (8KB, source-XOR-preswizzled); A-frags
// read f32 from LDS and split to bf16 hi/lo in-register; 16 nt x 4 mfma.
// acc layout (m89): col = nt*16+(l&15), row = w*16+(l>>4)*4+j.
// LN per row: 16-lane shfl groups (wave-local). Epilogue: rT[256][68]
// (all 64 rows) -> 2-phase scores/argmax (v0 code) -> table gather.
#define RS 68

__global__ __launch_bounds__(256) void hvq_main(
    const float* __restrict__ x,
    const unsigned short* __restrict__ Whg,
    const unsigned short* __restrict__ Wlg,
    const float* __restrict__ bl1, const float* __restrict__ H_all,
    const float* __restrict__ f_all, const int* __restrict__ idx1,
    const float* __restrict__ table, float* __restrict__ out){
  __shared__ float smem[RS*256 + 64];      // 69888 + 256 B
  unsigned short* WhL = (unsigned short*)smem;        // [0,16384) B: Wh [256][32]
  unsigned short* WlL = WhL + 8192;                   // [16384,32768) B
  float* xsF = smem + 8192;                           // [32768,40960) B: x [64][32] f32
  float* rT  = smem;                                  // epilogue alias
  int* kstar = (int*)&smem[RS*256];                   // 64 ints

  const int tid = threadIdx.x;
  const int w = tid >> 6, l = tid & 63;
  const int b  = blockIdx.y;
  const int t0 = blockIdx.x * 64;
  const int i1 = idx1[b];

  f32x4 acc[16];
  #pragma unroll
  for(int nt=0;nt<16;nt++) acc[nt] = (f32x4){0.f,0.f,0.f,0.f};

  float bn[16];
  #pragma unroll
  for(int nt=0;nt<16;nt++) bn[nt] = bl1[nt*16 + (l & 15)];

  const int arow = w*16 + (l & 15);        // A-frag row (block-relative)
  const int akc  = l >> 4;                 // k-chunk group 0..3
  const int rm   = arow & 7;               // x swizzle key

  for(int kt=0; kt<32; ++kt){
    // ---- stage W hi/lo bf16 slices (8 async insts) ----
    #pragma unroll
    for(int i=0;i<4;i++){
      const int c = i*256 + tid;
      const int col = c >> 2, ch = c & 3;
      const size_t go = (size_t)col*1024 + kt*32 + ch*8;   // ushort offset
      async_copy16((const float*)(Whg + go), (float*)WhL + c*4);
      async_copy16((const float*)(Wlg + go), (float*)WlL + c*4);
    }
    // ---- stage x f32 (2 async insts, source-preswizzled chunks) ----
    #pragma unroll
    for(int i=0;i<2;i++){
      const int c = i*256 + tid;
      const int row = c >> 3, pos = c & 7;
      const int q = pos ^ (row & 7);
      async_copy16(x + ((size_t)(b*2048 + t0 + row))*1024 + kt*32 + q*4,
                   xsF + c*4);
    }
    __syncthreads();   // staging visible

    // ---- A fragments: read f32 (swizzled slots), split to bf16 hi/lo ----
    const float4 a0 = *(const float4*)&xsF[arow*32 + (((akc<<1)    ) ^ rm)*4];
    const float4 a1 = *(const float4*)&xsF[arow*32 + (((akc<<1) + 1) ^ rm)*4];
    bf16x8 ah, al_;
    split_f32x8(a0, a1, ah, al_);

    #pragma unroll
    for(int nt=0;nt<16;nt++){
      const int coff = (nt*16 + (l & 15))*32 + (akc << 3);
      const bf16x8 bh  = *(const bf16x8*)&WhL[coff];
      const bf16x8 bl_ = *(const bf16x8*)&WlL[coff];
      acc[nt] = __builtin_amdgcn_mfma_f32_16x16x32_bf16(ah,  bh,  acc[nt], 0, 0, 0);
      acc[nt] = __builtin_amdgcn_mfma_f32_16x16x32_bf16(ah,  bl_, acc[nt], 0, 0, 0);
      acc[nt] = __builtin_amdgcn_mfma_f32_16x16x32_bf16(al_, bh,  acc[nt], 0, 0, 0);
      acc[nt] = __builtin_amdgcn_mfma_f32_16x16x32_bf16(al_, bl_, acc[nt], 0, 0, 0);
    }
    __syncthreads();   // compute done before restage
  }

  // ---- bias + LN(256) per row + ReLU (16-lane shfl groups) ----
  #pragma unroll
  for(int j=0;j<4;j++){
    float s = 0.f;
    #pragma unroll
    for(int nt=0;nt<16;nt++){ acc[nt][j] += bn[nt]; s += acc[nt][j]; }
    s += __shfl_xor(s,1); s += __shfl_xor(s,2); s += __shfl_xor(s,4); s += __shfl_xor(s,8);
    const float mean = s * (1.f/256.f);
    float d2 = 0.f;
    #pragma unroll
    for(int nt=0;nt<16;nt++){ const float dv = acc[nt][j] - mean; d2 += dv*dv; }
    d2 += __shfl_xor(d2,1); d2 += __shfl_xor(d2,2); d2 += __shfl_xor(d2,4); d2 += __shfl_xor(d2,8);
    const float inv = 1.f / sqrtf(d2*(1.f/256.f) + 1e-5f);
    #pragma unroll
    for(int nt=0;nt<16;nt++) acc[nt][j] = fmaxf((acc[nt][j]-mean)*inv, 0.f);
  }

  // ---- write rT[col][row] (64 rows, stride 68): acc[nt] = 4 rows, 1 col ----
  const int m0 = w*16 + (akc << 2);
  #pragma unroll
  for(int nt=0;nt<16;nt++){
    float4 o;
    o.x = acc[nt][0]; o.y = acc[nt][1]; o.z = acc[nt][2]; o.w = acc[nt][3];
    *(float4*)&rT[(nt*16 + (l & 15))*RS + m0] = o;
  }
  __syncthreads();

  // ---- scores + argmax (two 32-row phases over persistent rT) ----
  const int k = tid & 31, mg = tid >> 5;
  const float* Hb = H_all + (size_t)i1*256*32 + k;
  const float fk = f_all[i1*32 + k];

  #pragma unroll
  for(int h=0; h<2; h++){
    float s0=fk, s1=fk, s2=fk, s3=fk;
    #pragma unroll 4
    for(int n=0;n<256;n++){
      const float4 rmv = *(const float4*)&rT[n*RS + h*32 + mg*4];
      const float hv = Hb[(size_t)n*32];
      s0 = fmaf(rmv.x, hv, s0);
      s1 = fmaf(rmv.y, hv, s1);
      s2 = fmaf(rmv.z, hv, s2);
      s3 = fmaf(rmv.w, hv, s3);
    }
    float scv[4] = {s0, s1, s2, s3};
    #pragma unroll
    for(int j=0;j<4;j++){
      float best = scv[j]; int bi = k;
      #pragma unroll
      for(int off=16;off>=1;off>>=1){
        const float ov = __shfl_xor(best, off);
        const int   oi = __shfl_xor(bi, off);
        if(ov > best || (ov == best && oi < bi)){ best = ov; bi = oi; }
      }
      if(k == 0) kstar[h*32 + mg*4 + j] = bi;
    }
  }
  __syncthreads();

  float* ob = out + ((size_t)(b*2048 + t0))*256;
  for(int m=0;m<64;m++){
    const float v = table[((size_t)(i1*32 + kstar[m]))*256 + tid];
    ob[(size_t)m*256 + tid] = v;
  }
}

// ---------------------------------------------------------------------------
extern "C" void kernel_launch(void* const* d_in, const int* in_sizes, int n_in,
                              void* d_out, int out_size, void* d_ws, size_t ws_size,
                              hipStream_t stream){
  const float* x   = (const float*)d_in[0];
  const float* Wg1 = (const float*)d_in[1];
  const float* bg1 = (const float*)d_in[2];
  const float* Wg2 = (const float*)d_in[3];
  const float* bg2 = (const float*)d_in[4];
  const float* Wl1 = (const float*)d_in[5];
  const float* bl1 = (const float*)d_in[6];
  const float* Wl2 = (const float*)d_in[7];
  const float* bl2 = (const float*)d_in[8];
  const float* Wp  = (const float*)d_in[9];
  const float* bp  = (const float*)d_in[10];
  const float* cb1 = (const float*)d_in[11];
  const float* Wtb = (const float*)d_in[12];
  const float* btb = (const float*)d_in[13];
  const float* Wfb = (const float*)d_in[14];
  const float* bfb = (const float*)d_in[15];
  const float* cb2 = (const float*)d_in[16];
  const float* Wf  = (const float*)d_in[17];
  const float* bf  = (const float*)d_in[18];
  float* out = (float*)d_out;

  char* w = (char*)d_ws;
  double* psum   = (double*)w; w += (size_t)16*16*1024*8;   // 2 MB
  double* psumsq = (double*)w; w += (size_t)16*16*1024*8;   // 2 MB
  float*  Wl1T   = (float*)w;  w += (size_t)1024*256*4;     // 1 MB
  float*  Wg1T   = (float*)w;  w += (size_t)1024*256*4;     // 1 MB
  float*  WfT    = (float*)w;  w += (size_t)384*256*4;
  float*  WfbT   = (float*)w;  w += (size_t)64*256*4;
  float*  Wg2T   = (float*)w;  w += (size_t)256*128*4;
  float*  WpT    = (float*)w;  w += (size_t)128*128*4;
  float*  H_all  = (float*)w;  w += (size_t)8*256*32*4;     // 256 KB
  float*  f_all  = (float*)w;  w += (size_t)8*32*4;
  float*  table  = (float*)w;  w += (size_t)256*256*4;      // 256 KB
  int*    idx1   = (int*)w;    w += 64;
  unsigned short* Whg = (unsigned short*)w; w += (size_t)256*1024*2;  // 512 KB
  unsigned short* Wlg = (unsigned short*)w; w += (size_t)256*1024*2;  // 512 KB

  hvq_A<<<496, 256, 0, stream>>>(x, Wl1, Wg1, Wf, Wfb, Wg2, Wp, Wtb, Wl2, bl2, btb, cb2,
                                 psum, psumsq, Wl1T, Wg1T, WfT, WfbT, Wg2T, WpT,
                                 H_all, f_all, Whg, Wlg);
  hvq_B<<<272, 256, 0, stream>>>(psum, psumsq, Wg1T, bg1, Wg2T, bg2, WpT, bp, cb1, cb2,
                                 WfbT, bfb, WfT, bf, idx1, table);
  hvq_main<<<dim3(32,16), 256, 0, stream>>>(x, Whg, Wlg, bl1, H_all, f_all, idx1, table, out);
}